// Round 3
// baseline (414.232 us; speedup 1.0000x reference)
//
#include <hip/hip_runtime.h>

// ImageBuffer scatter, v3: plain cached stores (match the 6.3 TB/s fill's write
// path), moderate grid, 64 B/thread read once + up to 1 KB/thread written.
//   combined = concat(buffer[16], inputs[128]); out[b][k] = combined[b+1+k]
//   source frame j (1..143) -> outputs b in [max(0,j-16), min(127,j-1)],
//   output-frame index f = 15*b + j - 1 (stride 15 frames between stores).
// Eliminates both remaining suspects for a ~2.6 TB/s write cap:
//   - dispatch-rate (round 0: 98304 blocks)  -> now 1716 blocks
//   - nontemporal-store path (round 2)       -> now normal stores

typedef float f32x4 __attribute__((ext_vector_type(4)));

constexpr int BATCH     = 128;
constexpr int KBUF      = 16;
constexpr int FRAME_F32 = 128 * 128 * 3;        // 49152 floats per frame
constexpr int FRAME_F4  = FRAME_F32 / 4;        // 12288 float4 per frame
constexpr int BLOCK     = 256;
constexpr int VEC       = 4;                    // float4 per thread (64 B)
constexpr int CHUNK_F4  = BLOCK * VEC;          // 1024 float4 per block
constexpr int CHUNKS    = FRAME_F4 / CHUNK_F4;  // 12 chunks per source frame
constexpr int NSRC      = BATCH + KBUF - 1;     // source frames j = 1..143

__global__ __launch_bounds__(BLOCK)
void ImageBuffer_86784109183359_kernel(const f32x4* __restrict__ inputs,
                                       const f32x4* __restrict__ buffer,
                                       f32x4* __restrict__ out) {
    const int j     = blockIdx.x / CHUNKS + 1;        // source frame, 1..143
    const int chunk = blockIdx.x % CHUNKS;
    const int off   = chunk * CHUNK_F4 + threadIdx.x; // float4 offset in frame

    // Uniform per block — no divergence.
    const f32x4* __restrict__ src =
        (j < KBUF) ? (buffer + (size_t)j * FRAME_F4)
                   : (inputs + (size_t)(j - KBUF) * FRAME_F4);

    f32x4 v[VEC];
#pragma unroll
    for (int i = 0; i < VEC; ++i)
        v[i] = src[off + i * BLOCK];

    const int b_lo = (j > KBUF) ? (j - KBUF) : 0;
    const int b_hi = (j - 1 < BATCH - 1) ? (j - 1) : (BATCH - 1);

    size_t base = (size_t)(15 * b_lo + j - 1) * FRAME_F4 + off;
    const size_t stride = (size_t)15 * FRAME_F4;

    for (int b = b_lo; b <= b_hi; ++b) {
#pragma unroll
        for (int i = 0; i < VEC; ++i)
            out[base + i * BLOCK] = v[i];
        base += stride;
    }
}

extern "C" void kernel_launch(void* const* d_in, const int* in_sizes, int n_in,
                              void* d_out, int out_size, void* d_ws, size_t ws_size,
                              hipStream_t stream) {
    const f32x4* inputs = (const f32x4*)d_in[0];  // [128,128,128,3] fp32
    const f32x4* buffer = (const f32x4*)d_in[1];  // [16,128,128,3] fp32
    f32x4* out = (f32x4*)d_out;                   // [128,16,128,128,3] fp32

    const int grid = NSRC * CHUNKS;               // 143 * 12 = 1716 blocks

    ImageBuffer_86784109183359_kernel<<<grid, BLOCK, 0, stream>>>(inputs, buffer, out);
}